// Round 14
// baseline (23902.370 us; speedup 1.0000x reference)
//
#include <hip/hip_runtime.h>
#include <math.h>

// Problem dims
#define B_   128
#define S_   400
#define ENC_ 512
#define E_   256
#define H_   512
#define D_   128
#define P_   128
#define V_   30
#define T_   600

#define RSPLIT 144   // producer rows [0,144); consumer rows [144,lenb) <= 256

// Workspace layout (float units). Cross-block state TRANSPOSED [feature][batch].
#define KEYV_OFF 0                          // keyv, overwritten in-place with K2 by k_k2
#define VALV_OFF (KEYV_OFF + B_*S_*P_)
#define H1_OFF   (VALV_OFF + B_*S_*P_)      // 2 x [512][128]
#define H2T_OFF  (H1_OFF + 2*H_*B_)         // 2 x [128][128]
#define H2R_OFF  (H2T_OFF + 2*D_*B_)        // [128][128] row-major copy for P3
#define CTXT_OFF (H2R_OFF + B_*D_)          // [128][128]
#define CHR_OFF  (CTXT_OFF + P_*B_)
#define PV0_OFF  (CHR_OFF + B_)             // [128][128] producer partial PV
#define MS0_OFF  (PV0_OFF + B_*P_)          // [128][2]  producer (m, sum)
#define ES0_OFF  (MS0_OFF + 2*B_)           // [200]     producer exp-scores, item 0
#define FLAG_OFF (ES0_OFF + 200)            // [128*32] per-item flags, 128B apart
#define KB0_OFF  (FLAG_OFF + B_*32)         // [B*S] kb0[s] = bq . keyv[s]
#define WS_FLOATS (KB0_OFF + B_*S_)         // barrier ints live at ws[WS_FLOATS..]

#define PRED_N (B_*T_*V_)
#define NBLK 256
#define NTHR 512

// LDS float offsets (k-major weight slices, persistent)
#define W1_BASE 0                           // [896][16]
#define W2_BASE 14336                       // [640][16]
#define SCR     24576                       // per-phase scratch (13120 floats)
#define LDS_FLOATS (SCR + 13120)            // 37696 floats = 150784 B

__device__ __forceinline__ float sigm_(float x){ return 1.0f/(1.0f + expf(-x)); }

// --- agent-scope relaxed atomics (sc1): bypass caches, see coherence point ---
__device__ __forceinline__ float ldA(const float* p){
  return __hip_atomic_load(p, __ATOMIC_RELAXED, __HIP_MEMORY_SCOPE_AGENT);
}
__device__ __forceinline__ void stA(float* p, float v){
  __hip_atomic_store(p, v, __ATOMIC_RELAXED, __HIP_MEMORY_SCOPE_AGENT);
}
__device__ __forceinline__ int ldAi(const int* p){
  return __hip_atomic_load(p, __ATOMIC_RELAXED, __HIP_MEMORY_SCOPE_AGENT);
}
__device__ __forceinline__ void stAi(int* p, int v){
  __hip_atomic_store(p, v, __ATOMIC_RELAXED, __HIP_MEMORY_SCOPE_AGENT);
}
__device__ __forceinline__ void ldA2f(const float* p, float& a, float& b){
  unsigned long long v = __hip_atomic_load((const unsigned long long*)p,
                         __ATOMIC_RELAXED, __HIP_MEMORY_SCOPE_AGENT);
  a = __uint_as_float((unsigned)v);
  b = __uint_as_float((unsigned)(v>>32));
}

// ---- fence-free grid barrier, hardened; 16 leaves x 16 blocks ----
__device__ __forceinline__ void gbar(int* bar){
  asm volatile("s_waitcnt vmcnt(0)" ::: "memory");  // all sc1 stores at coherence point
  __syncthreads();
  if (threadIdx.x == 0){
    const int g0 = __hip_atomic_load(bar, __ATOMIC_RELAXED, __HIP_MEMORY_SCOPE_AGENT);
    asm volatile("" ::: "memory");
    int* leaf = bar + 64 + (blockIdx.x & 15)*32;
    int lo = __hip_atomic_fetch_add(leaf, 1, __ATOMIC_RELAXED, __HIP_MEMORY_SCOPE_AGENT);
    bool done = false;
    if (lo == 15){
      int ro = __hip_atomic_fetch_add(bar+32, 1, __ATOMIC_RELAXED, __HIP_MEMORY_SCOPE_AGENT);
      if (ro == 15){
        #pragma unroll
        for (int i=0;i<16;++i)
          __hip_atomic_store(bar+64+i*32, 0, __ATOMIC_RELAXED, __HIP_MEMORY_SCOPE_AGENT);
        __hip_atomic_store(bar+32, 0, __ATOMIC_RELAXED, __HIP_MEMORY_SCOPE_AGENT);
        asm volatile("s_waitcnt vmcnt(0)" ::: "memory");
        __hip_atomic_fetch_add(bar, 1, __ATOMIC_RELAXED, __HIP_MEMORY_SCOPE_AGENT);
        done = true;
      }
    }
    if (!done){
      while (__hip_atomic_load(bar, __ATOMIC_RELAXED, __HIP_MEMORY_SCOPE_AGENT) == g0)
        __builtin_amdgcn_s_sleep(4);
    }
  }
  __syncthreads();
}

// ---------------- precompute keyv/valv fp32 (proven) ------------------------------------
__global__ __launch_bounds__(256) void k_kv(const float* __restrict__ enc,
    const float* __restrict__ Wk, const float* __restrict__ bk,
    const float* __restrict__ Wv, const float* __restrict__ bv,
    float* __restrict__ ws)
{
  __shared__ float As[32][68];
  __shared__ float Bs[32][68];
  const int tid = threadIdx.x;
  const int tx = tid & 15, ty = tid >> 4;
  const int n0 = blockIdx.x * 64;
  const int c0 = blockIdx.y * 64;
  float acc[4][4] = {};
  for (int k0 = 0; k0 < ENC_; k0 += 32){
    #pragma unroll
    for (int i = 0; i < 8; ++i){
      int idx = tid + 256*i;
      int kk = idx & 31, nl = idx >> 5;
      As[kk][nl] = enc[(size_t)(n0+nl)*ENC_ + k0 + kk];
    }
    #pragma unroll
    for (int i = 0; i < 8; ++i){
      int idx = tid + 256*i;
      int kk = idx & 31, cl = idx >> 5;
      int c = c0 + cl; int p = c & 127;
      const float* W = (c < 128) ? Wk : Wv;
      Bs[kk][cl] = W[(size_t)p*ENC_ + k0 + kk];
    }
    __syncthreads();
    #pragma unroll
    for (int kk = 0; kk < 32; ++kk){
      float4 a4 = *(const float4*)&As[kk][ty*4];
      float4 b4 = *(const float4*)&Bs[kk][tx*4];
      float aa[4] = {a4.x, a4.y, a4.z, a4.w};
      float bb[4] = {b4.x, b4.y, b4.z, b4.w};
      #pragma unroll
      for (int i=0;i<4;++i)
        #pragma unroll
        for (int j=0;j<4;++j) acc[i][j] += aa[i]*bb[j];
    }
    __syncthreads();
  }
  float* keyv = ws + KEYV_OFF;
  float* valv = ws + VALV_OFF;
  #pragma unroll
  for (int i=0;i<4;++i){
    int n = n0 + ty*4 + i; int b = n / S_; int s = n - b*S_;
    #pragma unroll
    for (int j=0;j<4;++j){
      int c = c0 + tx*4 + j;
      float v = acc[i][j];
      if (c < 128) keyv[((size_t)b*S_+s)*P_ + c]       = v + bk[c];
      else         valv[((size_t)b*S_+s)*P_ + (c-128)] = v + bv[c-128];
    }
  }
}

// ------- k_k2: in-place keyv -> K2 (K2[n,d] = sum_p keyv[n,p] Wq[p,d]); kb0[n] = bq.keyv[n]
__global__ __launch_bounds__(256) void k_k2(const float* __restrict__ Wq,
    const float* __restrict__ bq, float* __restrict__ ws)
{
  __shared__ float As[32][68];    // [kk][row 0..63]
  __shared__ float Bs[32][132];   // [kk][d 0..127]
  __shared__ float bqs[32];
  float* keyv = ws + KEYV_OFF;
  float* kb0  = ws + KB0_OFF;
  const int tid = threadIdx.x;
  const int n0 = blockIdx.x * 64;          // 800 blocks
  const int ty = tid >> 4;                 // row-quad 0..15
  const int tx = tid & 15;                 // col-oct 0..15
  float acc[4][8] = {};
  float kbacc[4] = {};
  for (int k0 = 0; k0 < 128; k0 += 32){
    #pragma unroll
    for (int i = 0; i < 8; ++i){
      int idx = tid + 256*i;
      int kk = idx & 31, nl = idx >> 5;
      As[kk][nl] = keyv[(size_t)(n0+nl)*P_ + k0 + kk];
    }
    #pragma unroll
    for (int i = 0; i < 16; ++i){
      int idx = tid + 256*i;
      int kk = idx >> 7, d = idx & 127;
      Bs[kk][d] = Wq[(size_t)(k0+kk)*D_ + d];
    }
    if (tid < 32) bqs[tid] = bq[k0 + tid];
    __syncthreads();
    #pragma unroll
    for (int kk = 0; kk < 32; ++kk){
      float4 a4 = *(const float4*)&As[kk][ty*4];
      float aa[4] = {a4.x, a4.y, a4.z, a4.w};
      const float* br = &Bs[kk][tx*8];
      #pragma unroll
      for (int i=0;i<4;++i){
        #pragma unroll
        for (int j=0;j<8;++j) acc[i][j] += aa[i]*br[j];
      }
      if (tx == 0){
        float bv = bqs[kk];
        #pragma unroll
        for (int i=0;i<4;++i) kbacc[i] += bv*aa[i];
      }
    }
    __syncthreads();
  }
  #pragma unroll
  for (int i=0;i<4;++i){
    int row = n0 + ty*4 + i;
    *(float4*)&keyv[(size_t)row*P_ + tx*8]     = make_float4(acc[i][0],acc[i][1],acc[i][2],acc[i][3]);
    *(float4*)&keyv[(size_t)row*P_ + tx*8 + 4] = make_float4(acc[i][4],acc[i][5],acc[i][6],acc[i][7]);
    if (tx == 0) kb0[row] = kbacc[i];
  }
}

// ---------------- persistent kernel ------------------------------------------------------
__global__ __launch_bounds__(NTHR, 1) void k_persist(
    const float* __restrict__ embed,
    const float* __restrict__ Wih1, const float* __restrict__ Whh1,
    const float* __restrict__ bih1, const float* __restrict__ bhh1,
    const float* __restrict__ Wih2, const float* __restrict__ Whh2,
    const float* __restrict__ bih2, const float* __restrict__ bhh2,
    const float* __restrict__ Wq, const float* __restrict__ bq,
    const float* __restrict__ bchar, const int* __restrict__ lens,
    float* ws, float* out)
{
  extern __shared__ float smem[];
  const int tid = threadIdx.x;
  const int bid = blockIdx.x;
  int* bar = (int*)(ws + WS_FLOATS);

  float* ctxT = ws + CTXT_OFF;
  int*   chrg = (int*)(ws + CHR_OFF);
  float* h2R  = ws + H2R_OFF;
  float* pv0g = ws + PV0_OFF;
  float* ms0g = ws + MS0_OFF;
  float* es0g = ws + ES0_OFF;
  int*   flag = (int*)(ws + FLAG_OFF);
  float* kb0g = ws + KB0_OFF;

  float* Wl  = smem + W1_BASE;          // [896][16] k-major
  float* W2l = smem + W2_BASE;          // [640][16] k-major
  float* scr = smem + SCR;

  const int lane = tid & 63;
  const int so8  = tid >> 6;            // wave id

  // ---- phase-1 identity ----
  const int ib = bid & 1, ug = bid >> 1, b0 = ib*64;
  const int iq = lane & 15, rq = lane >> 4;
  const int u1 = tid >> 6;
  const int J1 = ug*4 + (u1 & 3);
  const int sA  = (tid & 31)*2;         // staging item pair (even)
  const int kbA = tid >> 5;             // 0..15, rows kbA*4+j

  // ---- phase-2 identity (bid<128) ----
  const int ig2 = bid & 3, ug2 = bid >> 2, b02 = ig2*32;
  const int iq2 = lane & 7, rq2 = lane >> 3;
  const int u2 = tid >> 5;
  const int J2 = ug2*4 + (u2 & 3);
  const int sB  = (tid & 15)*2;         // staging item pair (even, 32 items)
  const int kbB = tid >> 4;             // 0..31, rows kbB*2+j

  // ---- phase-3 identity: item = bid&127; h3=0 producer [0,144), h3=1 consumer [144,lenb)
  const int h3  = bid >> 7;
  const int it3 = bid & 127;
  const float* k2_3  = ws + KEYV_OFF + (size_t)it3*S_*P_;   // K2 after k_k2
  const float* valv3 = ws + VALV_OFF + (size_t)it3*S_*P_;
  const float* kb0_3 = kb0g + (size_t)it3*S_;
  const int lenb = lens[it3];
  const int cw  = h3 ? (lenb - RSPLIT) : RSPLIT;   // block's row count
  const int s0w = h3*RSPLIT;
  const float bqr  = bq[tid >> 2];
  const float bchr = ((tid >> 4) < V_) ? bchar[tid >> 4] : 0.f;

  // ================= one-time: weight slices into LDS (k-major) ============
  {
    const int r = tid & 15, kb = tid >> 4;
    const int R = (r >> 2)*H_ + ug*4 + (r & 3);
    for (int j = 0; j < 28; ++j){
      int k = kb*28 + j;
      float v = (k < 384) ? Wih1[(size_t)R*384 + k] : Whh1[(size_t)R*H_ + (k-384)];
      Wl[k*16 + r] = v;
    }
  }
  if (bid < 128){
    const int r = tid & 15, kb = tid >> 4;
    const int R = (r >> 2)*D_ + ug2*4 + (r & 3);
    for (int j = 0; j < 20; ++j){
      int k = kb*20 + j;
      float v = (k < 512) ? Wih2[(size_t)R*H_ + k] : Whh2[(size_t)R*D_ + (k-512)];
      W2l[k*16 + r] = v;
    }
  }
  __syncthreads();

  float c1r = 0.f, c2r = 0.f;
  float b1s[4], b2s[4];
  #pragma unroll
  for (int g=0; g<4; ++g){
    b1s[g] = bih1[g*H_ + J1] + bhh1[g*H_ + J1];
    b2s[g] = (bid < 128) ? (bih2[g*D_ + J2] + bhh2[g*D_ + J2]) : 0.f;
  }

  for (int t = 0; t < T_; ++t){
    // ================= Phase 1: LSTM1 (all 256 blocks) ===================
    {
      const float* h1oT = ws + H1_OFF + (size_t)(t&1)*H_*B_;
      float*       h1nT = ws + H1_OFF + (size_t)((t+1)&1)*H_*B_;
      float* Xs  = scr;                 // [64][64] swizzled rows
      float* red = scr + 4096;          // [8][16][68]
      int*   schs= (int*)(scr + 12800); // [64]

      if (tid < 64) schs[tid] = ldAi(chrg + b0 + tid);
      __syncthreads();
      const int chA = schs[sA], chB = schs[sA+1];

      float xr[4][8];
      auto LOADX = [&](int p, float* dst){
        if (p < 4){                      // embed panels (cached, per-item float4)
          const float4 va = *(const float4*)(embed + (size_t)chA*E_ + p*64 + kbA*4);
          const float4 vb = *(const float4*)(embed + (size_t)chB*E_ + p*64 + kbA*4);
          dst[0]=va.x; dst[1]=vb.x; dst[2]=va.y; dst[3]=vb.y;
          dst[4]=va.z; dst[5]=vb.z; dst[6]=va.w; dst[7]=vb.w;
        } else {                         // state panels: coalesced u64 sc1 loads
          const float* base = (p < 6) ? (ctxT + (size_t)(p*64-256)*B_)
                                      : (h1oT + (size_t)(p*64-384)*B_);
          #pragma unroll
          for (int j=0;j<4;++j)
            ldA2f(base + (size_t)(kbA*4+j)*B_ + b0 + sA, dst[j*2], dst[j*2+1]);
        }
      };
      LOADX(0,xr[0]); LOADX(1,xr[1]); LOADX(2,xr[2]); LOADX(3,xr[3]);

      float acc[4][4] = {};
      #pragma unroll
      for (int p = 0; p < 14; ++p){
        float* xc = xr[p&3];
        #pragma unroll
        for (int j=0;j<4;++j){           // swizzled b64 LDS writes (all 32 banks, 2/bank)
          const int kl = kbA*4 + j;
          *(float2*)&Xs[kl*64 + (((sA>>2)+kl)&15)*4 + (sA&3)]
            = make_float2(xc[j*2], xc[j*2+1]);
        }
        __syncthreads();
        if (p + 4 < 14) LOADX(p + 4, xr[p&3]);
        float4 xv[8], wv[8];
        #pragma unroll
        for (int it = 0; it < 8; ++it){  // batched ds_reads
          const int kl = so8*8 + it;
          xv[it] = *(const float4*)&Xs[kl*64 + ((iq + kl)&15)*4];
          wv[it] = *(const float4*)&Wl[(p*64 + kl)*16 + rq*4];
        }
        #pragma unroll
        for (int it = 0; it < 8; ++it){
          float xa[4] = {xv[it].x, xv[it].y, xv[it].z, xv[it].w};
          float wa[4] = {wv[it].x, wv[it].y, wv[it].z, wv[it].w};
          #pragma unroll
          for (int i=0;i<4;++i)
            #pragma unroll
            for (int j=0;j<4;++j) acc[i][j] += xa[i]*wa[j];
        }
        __syncthreads();
      }
      #pragma unroll
      for (int j=0;j<4;++j)
        *(float4*)&red[so8*1088 + (rq*4+j)*68 + iq*4]
          = make_float4(acc[0][j], acc[1][j], acc[2][j], acc[3][j]);
      __syncthreads();
      if (tid < 256){
        const int item = tid & 63;
        float gate[4];
        #pragma unroll
        for (int g=0; g<4; ++g){
          float s = 0.f;
          #pragma unroll
          for (int w=0; w<8; ++w) s += red[w*1088 + (g*4+(u1&3))*68 + item];
          gate[g] = s + b1s[g];
        }
        float cn = sigm_(gate[1])*c1r + sigm_(gate[0])*tanhf(gate[2]);
        float hn = sigm_(gate[3])*tanhf(cn);
        c1r = cn;
        stA(h1nT + (size_t)J1*B_ + b0 + item, hn);   // transposed, coalesced
      }
    }
    gbar(bar);

    // ================= Phase 2: LSTM2 (blocks 0..127) ====================
    if (bid < 128){
      const float* h1nT = ws + H1_OFF + (size_t)((t+1)&1)*H_*B_;
      const float* h2oT = ws + H2T_OFF + (size_t)(t&1)*D_*B_;
      float*       h2nT = ws + H2T_OFF + (size_t)((t+1)&1)*D_*B_;
      float* Xs2  = scr;                // [64][32] swizzled
      float* red2 = scr + 2048;         // [8][16][36]

      float xr2[4][4];
      auto LOADX2 = [&](int p, float* dst){
        const float* base = (p < 8) ? (h1nT + (size_t)(p*64)*B_)
                                    : (h2oT + (size_t)(p*64-512)*B_);
        #pragma unroll
        for (int j=0;j<2;++j)
          ldA2f(base + (size_t)(kbB*2+j)*B_ + b02 + sB, dst[j*2], dst[j*2+1]);
      };
      LOADX2(0,xr2[0]); LOADX2(1,xr2[1]); LOADX2(2,xr2[2]); LOADX2(3,xr2[3]);

      float acc2[4][2] = {};
      #pragma unroll
      for (int p = 0; p < 10; ++p){
        float* xc = xr2[p&3];
        #pragma unroll
        for (int j=0;j<2;++j){
          const int kl = kbB*2 + j;
          *(float2*)&Xs2[kl*32 + (((sB>>2)+kl)&7)*4 + (sB&3)]
            = make_float2(xc[j*2], xc[j*2+1]);
        }
        __syncthreads();
        if (p + 4 < 10) LOADX2(p + 4, xr2[p&3]);
        float4 xv2[8]; float2 wv2[8];
        #pragma unroll
        for (int it = 0; it < 8; ++it){
          const int kl = so8*8 + it;
          xv2[it] = *(const float4*)&Xs2[kl*32 + ((iq2 + kl)&7)*4];
          wv2[it] = *(const float2*)&W2l[(p*64 + kl)*16 + rq2*2];
        }
        #pragma unroll
        for (int it = 0; it < 8; ++it){
          float xa[4] = {xv2[it].x, xv2[it].y, xv2[it].z, xv2[it].w};
          #pragma unroll
          for (int i=0;i<4;++i){
            acc2[i][0] += xa[i]*wv2[it].x;
            acc2[i][1] += xa[i]*wv2[it].y;
          }
        }
        __syncthreads();
      }
      #pragma unroll
      for (int j=0;j<2;++j)
        *(float4*)&red2[so8*576 + (rq2*2+j)*36 + iq2*4]
          = make_float4(acc2[0][j], acc2[1][j], acc2[2][j], acc2[3][j]);
      __syncthreads();
      if (tid < 128){
        const int item = tid & 31;
        float gate[4];
        #pragma unroll
        for (int g=0; g<4; ++g){
          float s = 0.f;
          #pragma unroll
          for (int w=0; w<8; ++w) s += red2[w*576 + (g*4+(u2&3))*36 + item];
          gate[g] = s + b2s[g];
        }
        float cn = sigm_(gate[1])*c2r + sigm_(gate[0])*tanhf(gate[2]);
        float hn = sigm_(gate[3])*tanhf(cn);
        c2r = cn;
        stA(h2nT + (size_t)J2*B_ + b02 + item, hn);          // transposed (P2 staging)
        stA(h2R  + (size_t)(b02+item)*D_ + J2, hn);          // row-major (P3 gather)
      }
    }
    gbar(bar);

    // ================= Phase 3: attention split over ALL 256 blocks =========
    {
      float* es3  = scr;         // 260
      float* hs3  = scr + 260;   // 128
      float* qs3  = scr + 388;   // 128 (consumer combine only)
      float* redw = scr + 516;   // 16
      float* red33= scr + 532;   // 16*132 -> ends 2644
      float* pvc  = scr + 2644;  // 128
      float* oes3 = scr + 2772;  // 256
      float* pred3= scr + 3028;  // 32

      if (tid < 260) es3[tid] = 0.f;
      if (tid < 128) hs3[tid] = ldA(h2R + (size_t)it3*D_ + tid);
      __syncthreads();
      // scores: 2 threads/row; score = h2 . K2[s] + kb0[s]   (q-GEMV folded into K2)
      const int r2 = tid >> 1, hseg = tid & 1;
      float sv = -INFINITY;
      if (r2 < cw){
        const float4* kr = (const float4*)(k2_3 + (size_t)(s0w + r2)*P_ + hseg*64);
        float kb0v = kb0_3[s0w + r2];
        float a = 0.f;
        #pragma unroll 8
        for (int d=0; d<16; ++d){
          float4 kv = kr[d];
          float4 hv = *(const float4*)&hs3[hseg*64 + d*4];
          a += kv.x*hv.x + kv.y*hv.y + kv.z*hv.z + kv.w*hv.w;
        }
        a += __shfl_down(a, 1, 2);
        if (hseg == 0) sv = (a + kb0v) * 0.08838834764831845f;
      }
      float mv = sv;
      #pragma unroll
      for (int o=32; o; o>>=1) mv = fmaxf(mv, __shfl_xor(mv, o));
      if ((tid & 63) == 0) redw[tid >> 6] = mv;
      __syncthreads();
      const float mh = fmaxf(fmaxf(fmaxf(redw[0],redw[1]),fmaxf(redw[2],redw[3])),
                             fmaxf(fmaxf(redw[4],redw[5]),fmaxf(redw[6],redw[7])));
      float pvx = 0.f;
      if (r2 < cw && hseg == 0){ pvx = expf(sv - mh); es3[r2] = pvx; }
      float sm = pvx;
      #pragma unroll
      for (int o=32; o; o>>=1) sm += __shfl_xor(sm, o);
      if ((tid & 63) == 0) redw[8 + (tid >> 6)] = sm;
      __syncthreads();
      const float sumh = ((redw[8]+redw[9])+(redw[10]+redw[11]))
                       + ((redw[12]+redw[13])+(redw[14]+redw[15]));
      {                                  // partial PV over this block's window
        const int p4 = tid & 31, sg = tid >> 5;
        const int chunk = (cw + 15) >> 4;
        const int rbeg = sg*chunk, rend = min(rbeg + chunk, cw);
        float a0=0,a1=0,a2=0,a3=0;
        for (int r = rbeg; r < rend; ++r){
          float e = es3[r];
          float4 v = *(const float4*)(valv3 + (size_t)(s0w + r)*P_ + p4*4);
          a0 += e*v.x; a1 += e*v.y; a2 += e*v.z; a3 += e*v.w;
        }
        *(float4*)&red33[sg*132 + p4*4] = make_float4(a0,a1,a2,a3);
      }
      __syncthreads();

      if (h3 == 0){
        // ---- producer: publish partials; HARDENED flag raise (per-thread drain) ----
        if (tid < 128){
          float c = 0.f;
          #pragma unroll
          for (int sg=0; sg<16; ++sg) c += red33[sg*132 + tid];
          stA(pv0g + (size_t)it3*P_ + tid, c);
        }
        if (tid == 0){ stA(ms0g + it3*2, mh); stA(ms0g + it3*2 + 1, sumh); }
        if (it3 == 0 && tid < RSPLIT) stA(es0g + tid, es3[tid]);
        asm volatile("s_waitcnt vmcnt(0)" ::: "memory");   // MY stores at coherence point
        __syncthreads();                                   // => ALL block's stores are
        if (tid == 0) stAi(flag + it3*32, t + 1);          // flag strictly after
      } else {
        // ---- consumer: own partial -> wait -> combine -> outputs ----
        if (tid < 128){
          float c = 0.f;
          #pragma unroll
          for (int sg=0; sg<16; ++sg) c += red33[sg*132 + tid];
          pvc[tid] = c;
        }
        __syncthreads();
        if (tid == 0){
          while (ldAi(flag + it3*32) != t + 1) __builtin_amdgcn_s_sleep(1);
        }
        __syncthreads();
        asm volatile("" ::: "memory");
        {                                // q = Wq h2 + bq (off critical path now)
          const int r = tid >> 2, kq = tid & 3;
          const float* wr = Wq + (size_t)r*D_ + kq*32;
          float a = 0.f;
          #pragma unroll
          for (int j=0;j<8;++j){
            float4 wvq = *(const float4*)(wr + j*4);
            float4 hv = *(const float4*)&hs3[kq*32 + j*4];
            a += wvq.x*hv.x + wvq.y*hv.y + wvq.z*hv.z + wvq.w*hv.w;
          }
          a += __shfl_down(a, 2, 4);
          a += __shfl_down(a, 1, 4);
          if (kq == 0) qs3[r] = a + bqr;
        }
        __syncthreads();
        const float m0 = ldA(ms0g + it3*2), s0v = ldA(ms0g + it3*2 + 1);
        const float m  = fmaxf(m0, mh);
        const float e0 = expf(m0 - m), e1 = expf(mh - m);
        const float sum = s0v*e0 + sumh*e1;
        if (tid < 128){
          float c = (ldA(pv0g + (size_t)it3*P_ + tid)*e0 + pvc[tid]*e1) / sum;
          stA(ctxT + (size_t)tid*B_ + it3, c);
          oes3[tid] = qs3[tid]; oes3[128+tid] = c;
        }
        __syncthreads();
        {                                // pred + tied-embedding logits
          const int v = tid >> 4, k16 = tid & 15;
          float a = 0.f;
          if (v < V_){
            const float4* er = (const float4*)(embed + (size_t)v*E_ + k16*16);
            #pragma unroll
            for (int j=0;j<4;++j){
              float4 ev = er[j];
              float4 ov = *(const float4*)&oes3[k16*16 + j*4];
              a += ev.x*ov.x + ev.y*ov.y + ev.z*ov.z + ev.w*ov.w;
            }
          }
          a += __shfl_down(a, 8, 16);
          a += __shfl_down(a, 4, 16);
          a += __shfl_down(a, 2, 16);
          a += __shfl_down(a, 1, 16);
          if (v < V_ && k16 == 0){
            float pvv = a + bchr;
            pred3[v] = pvv;
            out[((size_t)it3*T_ + t)*V_ + v] = pvv;
          }
        }
        __syncthreads();
        if (tid < 32){                   // argmax (numpy first-index tie-break)
          float val = (tid < V_) ? pred3[tid] : -INFINITY;
          int idx = tid;
          #pragma unroll
          for (int o = 16; o > 0; o >>= 1){
            float ov = __shfl_down(val, o, 32);
            int oi = __shfl_down(idx, o, 32);
            if (ov > val || (ov == val && oi < idx)){ val = ov; idx = oi; }
          }
          if (tid == 0) stAi(chrg + it3, idx);
        }
        if (it3 == 0 && tid < S_){       // plot (rows >= lenb exactly 0)
          float v = (tid < RSPLIT) ? ldA(es0g + tid)*e0 : es3[tid - RSPLIT]*e1;
          out[PRED_N + (size_t)t*S_ + tid] = v / sum;
        }
      }
    }
    gbar(bar);
  }
}

extern "C" void kernel_launch(void* const* d_in, const int* in_sizes, int n_in,
                              void* d_out, int out_size, void* d_ws, size_t ws_size,
                              hipStream_t stream)
{
  (void)in_sizes; (void)n_in; (void)out_size; (void)ws_size;
  const float* enc   = (const float*)d_in[0];
  const int*   lens  = (const int*)d_in[1];
  const float* embed = (const float*)d_in[2];
  const float* Wih1  = (const float*)d_in[3];
  const float* Whh1  = (const float*)d_in[4];
  const float* bih1  = (const float*)d_in[5];
  const float* bhh1  = (const float*)d_in[6];
  const float* Wih2  = (const float*)d_in[7];
  const float* Whh2  = (const float*)d_in[8];
  const float* bih2  = (const float*)d_in[9];
  const float* bhh2  = (const float*)d_in[10];
  const float* Wk    = (const float*)d_in[11];
  const float* bk    = (const float*)d_in[12];
  const float* Wv    = (const float*)d_in[13];
  const float* bv    = (const float*)d_in[14];
  const float* Wq    = (const float*)d_in[15];
  const float* bq    = (const float*)d_in[16];
  const float* bchar = (const float*)d_in[17];
  float* out = (float*)d_out;
  float* ws  = (float*)d_ws;

  // zero recurrent state + partials + flags + kb0 + barrier region (replay-deterministic)
  hipMemsetAsync((char*)d_ws + (size_t)H1_OFF*sizeof(float), 0,
                 (size_t)(WS_FLOATS - H1_OFF)*sizeof(float) + 4096, stream);
  hipLaunchKernelGGL(k_kv, dim3(800,4), dim3(256), 0, stream, enc, Wk, bk, Wv, bv, ws);
  hipLaunchKernelGGL(k_k2, dim3(800),   dim3(256), 0, stream, Wq, bq, ws);

  // 150784 B dynamic LDS -> 1 block/CU, all 256 blocks co-resident (grid barrier safe)
  hipFuncSetAttribute((const void*)k_persist,
                      hipFuncAttributeMaxDynamicSharedMemorySize, LDS_FLOATS*4);
  hipLaunchKernelGGL(k_persist, dim3(NBLK), dim3(NTHR), LDS_FLOATS*4, stream,
                     embed, Wih1, Whh1, bih1, bhh1,
                     Wih2, Whh2, bih2, bhh2,
                     Wq, bq, bchar, lens, ws, out);
}

// Round 15
// 22188.475 us; speedup vs baseline: 1.0772x; 1.0772x over previous
//
#include <hip/hip_runtime.h>
#include <math.h>

// Problem dims
#define B_   128
#define S_   400
#define ENC_ 512
#define E_   256
#define H_   512
#define D_   128
#define P_   128
#define V_   30
#define T_   600

// Workspace layout (float units). Cross-block state TRANSPOSED [feature][batch].
#define KEYV_OFF 0
#define VALV_OFF (KEYV_OFF + B_*S_*P_)
#define H1_OFF   (VALV_OFF + B_*S_*P_)      // 2 x [512][128]
#define H2T_OFF  (H1_OFF + 2*H_*B_)         // 2 x [128][128]
#define H2R_OFF  (H2T_OFF + 2*D_*B_)        // [128][128] row-major copy for P3
#define CTXT_OFF (H2R_OFF + B_*D_)          // [128][128]
#define CHR_OFF  (CTXT_OFF + P_*B_)
#define PV0_OFF  (CHR_OFF + B_)             // [128][128] producer partial PV (rows 0-199)
#define MS0_OFF  (PV0_OFF + B_*P_)          // [128][2]  producer (m, sum)
#define ES0_OFF  (MS0_OFF + 2*B_)           // [200]     producer exp-scores, item 0 (plot)
#define FLAG_OFF (ES0_OFF + 200)            // [128*32] per-item flags, 128B apart
#define CNT_OFF  (FLAG_OFF + B_*32)         // [4*32] h2-ready counters (item-group), 128B apart
#define WS_FLOATS (CNT_OFF + 4*32)          // barrier ints live at ws[WS_FLOATS..]

#define PRED_N (B_*T_*V_)
#define NBLK 256
#define NTHR 512

// LDS float offsets (k-major weight slices, persistent)
#define W1_BASE 0                           // [896][16]
#define W2_BASE 14336                       // [640][16]
#define SCR     24576                       // per-phase scratch (13120 floats)
#define LDS_FLOATS (SCR + 13120)            // 37696 floats = 150784 B

__device__ __forceinline__ float sigm_(float x){ return 1.0f/(1.0f + expf(-x)); }

// --- agent-scope relaxed atomics (sc1): bypass caches, see coherence point ---
__device__ __forceinline__ float ldA(const float* p){
  return __hip_atomic_load(p, __ATOMIC_RELAXED, __HIP_MEMORY_SCOPE_AGENT);
}
__device__ __forceinline__ void stA(float* p, float v){
  __hip_atomic_store(p, v, __ATOMIC_RELAXED, __HIP_MEMORY_SCOPE_AGENT);
}
__device__ __forceinline__ int ldAi(const int* p){
  return __hip_atomic_load(p, __ATOMIC_RELAXED, __HIP_MEMORY_SCOPE_AGENT);
}
__device__ __forceinline__ void stAi(int* p, int v){
  __hip_atomic_store(p, v, __ATOMIC_RELAXED, __HIP_MEMORY_SCOPE_AGENT);
}
__device__ __forceinline__ void ldA2f(const float* p, float& a, float& b){
  unsigned long long v = __hip_atomic_load((const unsigned long long*)p,
                         __ATOMIC_RELAXED, __HIP_MEMORY_SCOPE_AGENT);
  a = __uint_as_float((unsigned)v);
  b = __uint_as_float((unsigned)(v>>32));
}

// ---- fence-free grid barrier, hardened (r10/r13-proven) ----
__device__ __forceinline__ void gbar(int* bar){
  asm volatile("s_waitcnt vmcnt(0)" ::: "memory");  // all sc1 stores at coherence point
  __syncthreads();
  if (threadIdx.x == 0){
    const int g0 = __hip_atomic_load(bar, __ATOMIC_RELAXED, __HIP_MEMORY_SCOPE_AGENT);
    asm volatile("" ::: "memory");
    int* leaf = bar + 64 + (blockIdx.x & 7)*32;
    int lo = __hip_atomic_fetch_add(leaf, 1, __ATOMIC_RELAXED, __HIP_MEMORY_SCOPE_AGENT);
    bool done = false;
    if (lo == 31){
      int ro = __hip_atomic_fetch_add(bar+32, 1, __ATOMIC_RELAXED, __HIP_MEMORY_SCOPE_AGENT);
      if (ro == 7){
        #pragma unroll
        for (int i=0;i<8;++i)
          __hip_atomic_store(bar+64+i*32, 0, __ATOMIC_RELAXED, __HIP_MEMORY_SCOPE_AGENT);
        __hip_atomic_store(bar+32, 0, __ATOMIC_RELAXED, __HIP_MEMORY_SCOPE_AGENT);
        asm volatile("s_waitcnt vmcnt(0)" ::: "memory");
        __hip_atomic_fetch_add(bar, 1, __ATOMIC_RELAXED, __HIP_MEMORY_SCOPE_AGENT);
        done = true;
      }
    }
    if (!done){
      while (__hip_atomic_load(bar, __ATOMIC_RELAXED, __HIP_MEMORY_SCOPE_AGENT) == g0)
        __builtin_amdgcn_s_sleep(4);
    }
  }
  __syncthreads();
}

// ---------------- precompute keyv/valv fp32 (proven) ------------------------------------
__global__ __launch_bounds__(256) void k_kv(const float* __restrict__ enc,
    const float* __restrict__ Wk, const float* __restrict__ bk,
    const float* __restrict__ Wv, const float* __restrict__ bv,
    float* __restrict__ ws)
{
  __shared__ float As[32][68];
  __shared__ float Bs[32][68];
  const int tid = threadIdx.x;
  const int tx = tid & 15, ty = tid >> 4;
  const int n0 = blockIdx.x * 64;
  const int c0 = blockIdx.y * 64;
  float acc[4][4] = {};
  for (int k0 = 0; k0 < ENC_; k0 += 32){
    #pragma unroll
    for (int i = 0; i < 8; ++i){
      int idx = tid + 256*i;
      int kk = idx & 31, nl = idx >> 5;
      As[kk][nl] = enc[(size_t)(n0+nl)*ENC_ + k0 + kk];
    }
    #pragma unroll
    for (int i = 0; i < 8; ++i){
      int idx = tid + 256*i;
      int kk = idx & 31, cl = idx >> 5;
      int c = c0 + cl; int p = c & 127;
      const float* W = (c < 128) ? Wk : Wv;
      Bs[kk][cl] = W[(size_t)p*ENC_ + k0 + kk];
    }
    __syncthreads();
    #pragma unroll
    for (int kk = 0; kk < 32; ++kk){
      float4 a4 = *(const float4*)&As[kk][ty*4];
      float4 b4 = *(const float4*)&Bs[kk][tx*4];
      float aa[4] = {a4.x, a4.y, a4.z, a4.w};
      float bb[4] = {b4.x, b4.y, b4.z, b4.w};
      #pragma unroll
      for (int i=0;i<4;++i)
        #pragma unroll
        for (int j=0;j<4;++j) acc[i][j] += aa[i]*bb[j];
    }
    __syncthreads();
  }
  float* keyv = ws + KEYV_OFF;
  float* valv = ws + VALV_OFF;
  #pragma unroll
  for (int i=0;i<4;++i){
    int n = n0 + ty*4 + i; int b = n / S_; int s = n - b*S_;
    #pragma unroll
    for (int j=0;j<4;++j){
      int c = c0 + tx*4 + j;
      float v = acc[i][j];
      if (c < 128) keyv[((size_t)b*S_+s)*P_ + c]       = v + bk[c];
      else         valv[((size_t)b*S_+s)*P_ + (c-128)] = v + bv[c-128];
    }
  }
}

// ---------------- persistent kernel ------------------------------------------------------
__global__ __launch_bounds__(NTHR, 1) void k_persist(
    const float* __restrict__ embed,
    const float* __restrict__ Wih1, const float* __restrict__ Whh1,
    const float* __restrict__ bih1, const float* __restrict__ bhh1,
    const float* __restrict__ Wih2, const float* __restrict__ Whh2,
    const float* __restrict__ bih2, const float* __restrict__ bhh2,
    const float* __restrict__ Wq, const float* __restrict__ bq,
    const float* __restrict__ bchar, const int* __restrict__ lens,
    float* ws, float* out)
{
  extern __shared__ float smem[];
  const int tid = threadIdx.x;
  const int bid = blockIdx.x;
  int* bar = (int*)(ws + WS_FLOATS);

  float* ctxT = ws + CTXT_OFF;
  int*   chrg = (int*)(ws + CHR_OFF);
  float* h2R  = ws + H2R_OFF;
  float* pv0g = ws + PV0_OFF;
  float* ms0g = ws + MS0_OFF;
  float* es0g = ws + ES0_OFF;
  int*   flag = (int*)(ws + FLAG_OFF);
  int*   cntg = (int*)(ws + CNT_OFF);

  float* Wl  = smem + W1_BASE;          // [896][16] k-major
  float* W2l = smem + W2_BASE;          // [640][16] k-major
  float* scr = smem + SCR;

  const int lane = tid & 63;
  const int so8  = tid >> 6;            // wave id

  // ---- phase-1 identity ----
  const int ib = bid & 1, ug = bid >> 1, b0 = ib*64;
  const int iq = lane & 15, rq = lane >> 4;
  const int u1 = tid >> 6;
  const int J1 = ug*4 + (u1 & 3);
  const int sA  = (tid & 31)*2;         // staging item pair (even)
  const int kbA = tid >> 5;             // 0..15, rows kbA*4+j

  // ---- phase-2 identity (bid<128) ----
  const int ig2 = bid & 3, ug2 = bid >> 2, b02 = ig2*32;
  const int iq2 = lane & 7, rq2 = lane >> 3;
  const int u2 = tid >> 5;
  const int J2 = ug2*4 + (u2 & 3);
  const int sB  = (tid & 15)*2;         // staging item pair (even, 32 items)
  const int kbB = tid >> 4;             // 0..31, rows kbB*2+j

  // ---- phase-3 identity: item = bid&127; h3=0 producer (rows 0-199), h3=1 consumer ----
  const int h3  = bid >> 7;
  const int it3 = bid & 127;
  const float* keyv3 = ws + KEYV_OFF + (size_t)it3*S_*P_;
  const float* valv3 = ws + VALV_OFF + (size_t)it3*S_*P_;
  const int lenb = lens[it3];
  const int cw  = h3 ? (lenb - 200) : 200;    // this block's row count (lens in [200,400])
  const int s0w = h3*200;
  const float bqr  = bq[tid >> 2];
  const float bchr = ((tid >> 4) < V_) ? bchar[tid >> 4] : 0.f;

  // ================= one-time: weight slices into LDS (k-major) ============
  {
    const int r = tid & 15, kb = tid >> 4;
    const int R = (r >> 2)*H_ + ug*4 + (r & 3);
    for (int j = 0; j < 28; ++j){
      int k = kb*28 + j;
      float v = (k < 384) ? Wih1[(size_t)R*384 + k] : Whh1[(size_t)R*H_ + (k-384)];
      Wl[k*16 + r] = v;
    }
  }
  if (bid < 128){
    const int r = tid & 15, kb = tid >> 4;
    const int R = (r >> 2)*D_ + ug2*4 + (r & 3);
    for (int j = 0; j < 20; ++j){
      int k = kb*20 + j;
      float v = (k < 512) ? Wih2[(size_t)R*H_ + k] : Whh2[(size_t)R*D_ + (k-512)];
      W2l[k*16 + r] = v;
    }
  }
  __syncthreads();

  float c1r = 0.f, c2r = 0.f;
  float b1s[4], b2s[4];
  #pragma unroll
  for (int g=0; g<4; ++g){
    b1s[g] = bih1[g*H_ + J1] + bhh1[g*H_ + J1];
    b2s[g] = (bid < 128) ? (bih2[g*D_ + J2] + bhh2[g*D_ + J2]) : 0.f;
  }

  for (int t = 0; t < T_; ++t){
    // ================= Phase 1: LSTM1 (all 256 blocks) ===================
    {
      const float* h1oT = ws + H1_OFF + (size_t)(t&1)*H_*B_;
      float*       h1nT = ws + H1_OFF + (size_t)((t+1)&1)*H_*B_;
      float* Xs  = scr;                 // [64][64] swizzled rows
      float* red = scr + 4096;          // [8][16][68]
      int*   schs= (int*)(scr + 12800); // [64]

      if (tid < 64) schs[tid] = ldAi(chrg + b0 + tid);
      __syncthreads();
      const int chA = schs[sA], chB = schs[sA+1];

      float xr[4][8];
      auto LOADX = [&](int p, float* dst){
        if (p < 4){                      // embed panels (cached, per-item float4)
          const float4 va = *(const float4*)(embed + (size_t)chA*E_ + p*64 + kbA*4);
          const float4 vb = *(const float4*)(embed + (size_t)chB*E_ + p*64 + kbA*4);
          dst[0]=va.x; dst[1]=vb.x; dst[2]=va.y; dst[3]=vb.y;
          dst[4]=va.z; dst[5]=vb.z; dst[6]=va.w; dst[7]=vb.w;
        } else {                         // state panels: coalesced u64 sc1 loads
          const float* base = (p < 6) ? (ctxT + (size_t)(p*64-256)*B_)
                                      : (h1oT + (size_t)(p*64-384)*B_);
          #pragma unroll
          for (int j=0;j<4;++j)
            ldA2f(base + (size_t)(kbA*4+j)*B_ + b0 + sA, dst[j*2], dst[j*2+1]);
        }
      };
      LOADX(0,xr[0]); LOADX(1,xr[1]); LOADX(2,xr[2]); LOADX(3,xr[3]);

      float acc[4][4] = {};
      #pragma unroll
      for (int p = 0; p < 14; ++p){
        float* xc = xr[p&3];
        #pragma unroll
        for (int j=0;j<4;++j){           // swizzled b64 LDS writes (all 32 banks, 2/bank)
          const int kl = kbA*4 + j;
          *(float2*)&Xs[kl*64 + (((sA>>2)+kl)&15)*4 + (sA&3)]
            = make_float2(xc[j*2], xc[j*2+1]);
        }
        __syncthreads();
        if (p + 4 < 14) LOADX(p + 4, xr[p&3]);
        float4 xv[8], wv[8];
        #pragma unroll
        for (int it = 0; it < 8; ++it){  // batched ds_reads
          const int kl = so8*8 + it;
          xv[it] = *(const float4*)&Xs[kl*64 + ((iq + kl)&15)*4];
          wv[it] = *(const float4*)&Wl[(p*64 + kl)*16 + rq*4];
        }
        #pragma unroll
        for (int it = 0; it < 8; ++it){
          float xa[4] = {xv[it].x, xv[it].y, xv[it].z, xv[it].w};
          float wa[4] = {wv[it].x, wv[it].y, wv[it].z, wv[it].w};
          #pragma unroll
          for (int i=0;i<4;++i)
            #pragma unroll
            for (int j=0;j<4;++j) acc[i][j] += xa[i]*wa[j];
        }
        __syncthreads();
      }
      #pragma unroll
      for (int j=0;j<4;++j)
        *(float4*)&red[so8*1088 + (rq*4+j)*68 + iq*4]
          = make_float4(acc[0][j], acc[1][j], acc[2][j], acc[3][j]);
      __syncthreads();
      if (tid < 256){
        const int item = tid & 63;
        float gate[4];
        #pragma unroll
        for (int g=0; g<4; ++g){
          float s = 0.f;
          #pragma unroll
          for (int w=0; w<8; ++w) s += red[w*1088 + (g*4+(u1&3))*68 + item];
          gate[g] = s + b1s[g];
        }
        float cn = sigm_(gate[1])*c1r + sigm_(gate[0])*tanhf(gate[2]);
        float hn = sigm_(gate[3])*tanhf(cn);
        c1r = cn;
        stA(h1nT + (size_t)J1*B_ + b0 + item, hn);   // transposed, coalesced
      }
    }
    gbar(bar);

    // ================= Phase 2: LSTM2 (blocks 0..127); consumers skip ahead ==
    if (bid < 128){
      const float* h1nT = ws + H1_OFF + (size_t)((t+1)&1)*H_*B_;
      const float* h2oT = ws + H2T_OFF + (size_t)(t&1)*D_*B_;
      float*       h2nT = ws + H2T_OFF + (size_t)((t+1)&1)*D_*B_;
      float* Xs2  = scr;                // [64][32] swizzled
      float* red2 = scr + 2048;         // [8][16][36]

      float xr2[4][4];
      auto LOADX2 = [&](int p, float* dst){
        const float* base = (p < 8) ? (h1nT + (size_t)(p*64)*B_)
                                    : (h2oT + (size_t)(p*64-512)*B_);
        #pragma unroll
        for (int j=0;j<2;++j)
          ldA2f(base + (size_t)(kbB*2+j)*B_ + b02 + sB, dst[j*2], dst[j*2+1]);
      };
      LOADX2(0,xr2[0]); LOADX2(1,xr2[1]); LOADX2(2,xr2[2]); LOADX2(3,xr2[3]);

      float acc2[4][2] = {};
      #pragma unroll
      for (int p = 0; p < 10; ++p){
        float* xc = xr2[p&3];
        #pragma unroll
        for (int j=0;j<2;++j){
          const int kl = kbB*2 + j;
          *(float2*)&Xs2[kl*32 + (((sB>>2)+kl)&7)*4 + (sB&3)]
            = make_float2(xc[j*2], xc[j*2+1]);
        }
        __syncthreads();
        if (p + 4 < 10) LOADX2(p + 4, xr2[p&3]);
        float4 xv2[8]; float2 wv2[8];
        #pragma unroll
        for (int it = 0; it < 8; ++it){
          const int kl = so8*8 + it;
          xv2[it] = *(const float4*)&Xs2[kl*32 + ((iq2 + kl)&7)*4];
          wv2[it] = *(const float2*)&W2l[(p*64 + kl)*16 + rq2*2];
        }
        #pragma unroll
        for (int it = 0; it < 8; ++it){
          float xa[4] = {xv2[it].x, xv2[it].y, xv2[it].z, xv2[it].w};
          #pragma unroll
          for (int i=0;i<4;++i){
            acc2[i][0] += xa[i]*wv2[it].x;
            acc2[i][1] += xa[i]*wv2[it].y;
          }
        }
        __syncthreads();
      }
      #pragma unroll
      for (int j=0;j<2;++j)
        *(float4*)&red2[so8*576 + (rq2*2+j)*36 + iq2*4]
          = make_float4(acc2[0][j], acc2[1][j], acc2[2][j], acc2[3][j]);
      __syncthreads();
      if (tid < 128){
        const int item = tid & 31;
        float gate[4];
        #pragma unroll
        for (int g=0; g<4; ++g){
          float s = 0.f;
          #pragma unroll
          for (int w=0; w<8; ++w) s += red2[w*576 + (g*4+(u2&3))*36 + item];
          gate[g] = s + b2s[g];
        }
        float cn = sigm_(gate[1])*c2r + sigm_(gate[0])*tanhf(gate[2]);
        float hn = sigm_(gate[3])*tanhf(cn);
        c2r = cn;
        stA(h2nT + (size_t)J2*B_ + b02 + item, hn);          // transposed (P2 staging)
        stA(h2R  + (size_t)(b02+item)*D_ + J2, hn);          // row-major (P3 gather)
      }
      // ---- h2-ready publish (replaces gbar#2): hardened per-thread drain ----
      asm volatile("s_waitcnt vmcnt(0)" ::: "memory");
      __syncthreads();
      if (tid == 0)
        (void)__hip_atomic_fetch_add(cntg + ig2*32, 1,
                                     __ATOMIC_RELAXED, __HIP_MEMORY_SCOPE_AGENT);
    }

    // ================= Phase 3: attention split over ALL 256 blocks =========
    {
      float* es3  = scr;         // 208
      float* hs3  = scr + 208;   // 128
      float* qs3  = scr + 336;   // 128
      float* redw = scr + 464;   // 16
      float* red33= scr + 480;   // 16*132 -> ends 2592
      float* pvc  = scr + 2592;  // 128
      float* oes3 = scr + 2720;  // 256
      float* pred3= scr + 2976;  // 32

      // wait until this item's h2 group is fully published (32 P2 blocks)
      if (tid == 0){
        while (ldAi(cntg + (it3 >> 5)*32) < 32*(t+1)) __builtin_amdgcn_s_sleep(1);
      }
      __syncthreads();
      asm volatile("" ::: "memory");

      if (tid < 208) es3[tid] = 0.f;
      if (tid < 128) hs3[tid] = ldA(h2R + (size_t)it3*D_ + tid);
      __syncthreads();
      {                                  // q = Wq h2 + bq (both halves, redundant)
        const int r = tid >> 2, kq = tid & 3;
        const float* wr = Wq + (size_t)r*D_ + kq*32;
        float a = 0.f;
        #pragma unroll
        for (int j=0;j<8;++j){
          float4 wvq = *(const float4*)(wr + j*4);
          float4 hv = *(const float4*)&hs3[kq*32 + j*4];
          a += wvq.x*hv.x + wvq.y*hv.y + wvq.z*hv.z + wvq.w*hv.w;
        }
        a += __shfl_down(a, 2, 4);
        a += __shfl_down(a, 1, 4);
        if (kq == 0) qs3[r] = a + bqr;
      }
      __syncthreads();
      // scores: 2 threads/row over this block's window
      const int r2 = tid >> 1, hseg = tid & 1;
      float sv = -INFINITY;
      if (r2 < cw){
        const float4* kr = (const float4*)(keyv3 + (size_t)(s0w + r2)*P_ + hseg*64);
        float a = 0.f;
        #pragma unroll 8
        for (int d=0; d<16; ++d){
          float4 kv = kr[d];
          float4 qv = *(const float4*)&qs3[hseg*64 + d*4];
          a += kv.x*qv.x + kv.y*qv.y + kv.z*qv.z + kv.w*qv.w;
        }
        a += __shfl_down(a, 1, 2);
        if (hseg == 0) sv = a * 0.08838834764831845f;
      }
      float mv = sv;
      #pragma unroll
      for (int o=32; o; o>>=1) mv = fmaxf(mv, __shfl_xor(mv, o));
      if ((tid & 63) == 0) redw[tid >> 6] = mv;
      __syncthreads();
      const float mh = fmaxf(fmaxf(fmaxf(redw[0],redw[1]),fmaxf(redw[2],redw[3])),
                             fmaxf(fmaxf(redw[4],redw[5]),fmaxf(redw[6],redw[7])));
      float pvx = 0.f;
      if (r2 < cw && hseg == 0){ pvx = expf(sv - mh); es3[r2] = pvx; }
      float sm = pvx;
      #pragma unroll
      for (int o=32; o; o>>=1) sm += __shfl_xor(sm, o);
      if ((tid & 63) == 0) redw[8 + (tid >> 6)] = sm;
      __syncthreads();
      const float sumh = ((redw[8]+redw[9])+(redw[10]+redw[11]))
                       + ((redw[12]+redw[13])+(redw[14]+redw[15]));
      {                                  // partial PV over this block's window
        const int p4 = tid & 31, sg = tid >> 5;
        const int rbeg = sg*13, rend = min(rbeg + 13, cw);
        float a0=0,a1=0,a2=0,a3=0;
        for (int r = rbeg; r < rend; ++r){
          float e = es3[r];
          float4 v = *(const float4*)(valv3 + (size_t)(s0w + r)*P_ + p4*4);
          a0 += e*v.x; a1 += e*v.y; a2 += e*v.z; a3 += e*v.w;
        }
        *(float4*)&red33[sg*132 + p4*4] = make_float4(a0,a1,a2,a3);
      }
      __syncthreads();

      if (h3 == 0){
        // ---- producer: publish partials; HARDENED flag raise (per-thread drain) ----
        if (tid < 128){
          float c = 0.f;
          #pragma unroll
          for (int sg=0; sg<16; ++sg) c += red33[sg*132 + tid];
          stA(pv0g + (size_t)it3*P_ + tid, c);
        }
        if (tid == 0){ stA(ms0g + it3*2, mh); stA(ms0g + it3*2 + 1, sumh); }
        if (it3 == 0 && tid < 200) stA(es0g + tid, es3[tid]);
        asm volatile("s_waitcnt vmcnt(0)" ::: "memory");   // MY stores at coherence point
        __syncthreads();                                   // => ALL block's stores are
        if (tid == 0) stAi(flag + it3*32, t + 1);          // flag strictly after
      } else {
        // ---- consumer: own partial -> wait -> combine -> outputs ----
        if (tid < 128){
          float c = 0.f;
          #pragma unroll
          for (int sg=0; sg<16; ++sg) c += red33[sg*132 + tid];
          pvc[tid] = c;
        }
        __syncthreads();
        if (tid == 0){
          while (ldAi(flag + it3*32) != t + 1) __builtin_amdgcn_s_sleep(1);
        }
        __syncthreads();
        asm volatile("" ::: "memory");
        const float m0 = ldA(ms0g + it3*2), s0v = ldA(ms0g + it3*2 + 1);
        const float m  = fmaxf(m0, mh);
        const float e0 = expf(m0 - m), e1 = expf(mh - m);    // mh=-inf -> e1=0
        const float sum = s0v*e0 + sumh*e1;
        if (tid < 128){
          float c = (ldA(pv0g + (size_t)it3*P_ + tid)*e0 + pvc[tid]*e1) / sum;
          stA(ctxT + (size_t)tid*B_ + it3, c);
          oes3[tid] = qs3[tid]; oes3[128+tid] = c;
        }
        __syncthreads();
        {                                // pred + tied-embedding logits
          const int v = tid >> 4, k16 = tid & 15;
          float a = 0.f;
          if (v < V_){
            const float4* er = (const float4*)(embed + (size_t)v*E_ + k16*16);
            #pragma unroll
            for (int j=0;j<4;++j){
              float4 ev = er[j];
              float4 ov = *(const float4*)&oes3[k16*16 + j*4];
              a += ev.x*ov.x + ev.y*ov.y + ev.z*ov.z + ev.w*ov.w;
            }
          }
          a += __shfl_down(a, 8, 16);
          a += __shfl_down(a, 4, 16);
          a += __shfl_down(a, 2, 16);
          a += __shfl_down(a, 1, 16);
          if (v < V_ && k16 == 0){
            float pvv = a + bchr;
            pred3[v] = pvv;
            out[((size_t)it3*T_ + t)*V_ + v] = pvv;
          }
        }
        __syncthreads();
        if (tid < 32){                   // argmax (numpy first-index tie-break)
          float val = (tid < V_) ? pred3[tid] : -INFINITY;
          int idx = tid;
          #pragma unroll
          for (int o = 16; o > 0; o >>= 1){
            float ov = __shfl_down(val, o, 32);
            int oi = __shfl_down(idx, o, 32);
            if (ov > val || (ov == val && oi < idx)){ val = ov; idx = oi; }
          }
          if (tid == 0) stAi(chrg + it3, idx);
        }
        if (it3 == 0 && tid < S_){       // plot (rows >= lenb exactly 0)
          float v = (tid < 200) ? ldA(es0g + tid)*e0 : es3[tid - 200]*e1;
          out[PRED_N + (size_t)t*S_ + tid] = v / sum;
        }
      }
    }
    gbar(bar);
  }
}

extern "C" void kernel_launch(void* const* d_in, const int* in_sizes, int n_in,
                              void* d_out, int out_size, void* d_ws, size_t ws_size,
                              hipStream_t stream)
{
  (void)in_sizes; (void)n_in; (void)out_size; (void)ws_size;
  const float* enc   = (const float*)d_in[0];
  const int*   lens  = (const int*)d_in[1];
  const float* embed = (const float*)d_in[2];
  const float* Wih1  = (const float*)d_in[3];
  const float* Whh1  = (const float*)d_in[4];
  const float* bih1  = (const float*)d_in[5];
  const float* bhh1  = (const float*)d_in[6];
  const float* Wih2  = (const float*)d_in[7];
  const float* Whh2  = (const float*)d_in[8];
  const float* bih2  = (const float*)d_in[9];
  const float* bhh2  = (const float*)d_in[10];
  const float* Wk    = (const float*)d_in[11];
  const float* bk    = (const float*)d_in[12];
  const float* Wv    = (const float*)d_in[13];
  const float* bv    = (const float*)d_in[14];
  const float* Wq    = (const float*)d_in[15];
  const float* bq    = (const float*)d_in[16];
  const float* bchar = (const float*)d_in[17];
  float* out = (float*)d_out;
  float* ws  = (float*)d_ws;

  // zero recurrent state + partials + flags + counters + barrier region
  hipMemsetAsync((char*)d_ws + (size_t)H1_OFF*sizeof(float), 0,
                 (size_t)(WS_FLOATS - H1_OFF)*sizeof(float) + 2048, stream);
  hipLaunchKernelGGL(k_kv, dim3(800,4), dim3(256), 0, stream, enc, Wk, bk, Wv, bv, ws);

  // 150784 B dynamic LDS -> 1 block/CU, all 256 blocks co-resident (grid barrier safe)
  hipFuncSetAttribute((const void*)k_persist,
                      hipFuncAttributeMaxDynamicSharedMemorySize, LDS_FLOATS*4);
  hipLaunchKernelGGL(k_persist, dim3(NBLK), dim3(NTHR), LDS_FLOATS*4, stream,
                     embed, Wih1, Whh1, bih1, bhh1,
                     Wih2, Whh2, bih2, bhh2,
                     Wq, bq, bchar, lens, ws, out);
}